// Round 16
// baseline (6253.843 us; speedup 1.0000x reference)
//
#include <hip/hip_runtime.h>
#include <math.h>

#define NN 262144
#define EE 2097152
#define BB 16
#define SS 7744
#define GG 484
#define NSLOT (SS*484)
#define NRANGE 128
#define NAB 512
#define ACH 4096

__device__ __forceinline__ float eluf(float x){ return x > 0.f ? x : expm1f(x); }

// ---------------- generic scans ----------------
__global__ __launch_bounds__(256) void k_scan1(const int* __restrict__ in, int* __restrict__ out,
                                               int* __restrict__ bsum, int n)
{
  __shared__ int sh[256];
  int t = threadIdx.x, gid = blockIdx.x*256 + t;
  int v = (gid < n) ? in[gid] : 0;
  sh[t] = v; __syncthreads();
  for (int off=1; off<256; off<<=1){
    int tmp = (t >= off) ? sh[t-off] : 0;
    __syncthreads();
    sh[t] += tmp;
    __syncthreads();
  }
  if (gid < n) out[gid] = sh[t] - v;
  if (t == 255) bsum[blockIdx.x] = sh[255];
}

__global__ __launch_bounds__(1024) void k_scan2(int* __restrict__ bsum, int nb)
{
  __shared__ int sh[1024];
  int t = threadIdx.x;
  int v = (t < nb) ? bsum[t] : 0;
  sh[t] = v; __syncthreads();
  for (int off=1; off<1024; off<<=1){
    int tmp = (t >= off) ? sh[t-off] : 0;
    __syncthreads();
    sh[t] += tmp;
    __syncthreads();
  }
  if (t < nb) bsum[t] = sh[t] - v;
  if (t == nb-1) bsum[1024] = sh[t];
}

__global__ __launch_bounds__(256) void k_scan3(int* __restrict__ out, const int* __restrict__ bsum, int n)
{
  int gid = blockIdx.x*256 + threadIdx.x;
  if (gid < n) out[gid] += bsum[blockIdx.x];
  if (gid == 0) out[n] = bsum[1024];
}

// ---------------- atomic-free CSR build: 2-level counting sort ----------------
__global__ __launch_bounds__(256) void k_hist(const int* __restrict__ dst, int* __restrict__ hist)
{
  __shared__ unsigned h[NRANGE];
  int t = threadIdx.x, b = blockIdx.x;
  if (t < NRANGE) h[t] = 0;
  __syncthreads();
  int base = b*ACH;
  for (int e = base + t; e < base + ACH; e += 256){
    int d = __builtin_nontemporal_load(dst + e);
    atomicAdd(&h[d >> 11], 1u);
  }
  __syncthreads();
  if (t < NRANGE) hist[t*NAB + b] = (int)h[t];
}

__global__ __launch_bounds__(256) void k_bscat(const int* __restrict__ src, const int* __restrict__ dst,
                          const float2* __restrict__ ea, const int* __restrict__ histS,
                          uint2* __restrict__ recs)
{
  __shared__ unsigned cur[NRANGE];
  int t = threadIdx.x, b = blockIdx.x;
  if (t < NRANGE) cur[t] = (unsigned)histS[t*NAB + b];
  __syncthreads();
  int base = b*ACH;
  for (int e = base + t; e < base + ACH; e += 256){
    int d = __builtin_nontemporal_load(dst + e);
    int sv = __builtin_nontemporal_load(src + e);
    float2 f = ea[e];
    unsigned ux = (unsigned)(fminf(fmaxf(f.x, 0.f), 1.f)*65535.f + 0.5f);
    unsigned uy = (unsigned)(fminf(fmaxf(f.y, 0.f), 1.f)*65535.f + 0.5f);
    unsigned pos = atomicAdd(&cur[d >> 11], 1u);
    uint2 rec;
    rec.x = (unsigned)sv | ((unsigned)(d & 2047) << 18);
    rec.y = (uy << 16) | ux;
    recs[pos] = rec;
  }
}

__global__ __launch_bounds__(256) void k_csrb(const int* __restrict__ histS, const uint2* __restrict__ recs,
                          int* __restrict__ rowstart, uint2* __restrict__ csr)
{
  __shared__ unsigned cnt[2048];
  __shared__ unsigned psum[256];
  int t = threadIdx.x, r = blockIdx.x;
  int rs = histS[r*NAB];
  int reE = histS[(r+1)*NAB];
  for (int i = t; i < 2048; i += 256) cnt[i] = 0;
  __syncthreads();
  for (int i = rs + t; i < reE; i += 256){
    unsigned rx = recs[i].x;
    atomicAdd(&cnt[rx >> 18], 1u);
  }
  __syncthreads();
  unsigned loc[8], run = 0;
  #pragma unroll
  for (int j=0;j<8;j++){ loc[j] = run; run += cnt[t*8+j]; }
  psum[t] = run; __syncthreads();
  for (int off=1; off<256; off<<=1){
    unsigned v = (t >= off) ? psum[t-off] : 0;
    __syncthreads();
    psum[t] += v;
    __syncthreads();
  }
  unsigned basep = psum[t] - run;
  #pragma unroll
  for (int j=0;j<8;j++) cnt[t*8+j] = basep + loc[j];
  __syncthreads();
  for (int i = t; i < 2048; i += 256) rowstart[r*2048 + i] = rs + (int)cnt[i];
  if (r == NRANGE-1 && t == 0) rowstart[NN] = EE;
  __syncthreads();
  for (int i = rs + t; i < reE; i += 256){
    uint2 rec = recs[i];
    unsigned dl = rec.x >> 18;
    unsigned slot = atomicAdd(&cnt[dl], 1u);
    uint2 o; o.x = rec.x & 0x3FFFFu; o.y = rec.y;
    csr[(size_t)rs + slot] = o;
  }
}

// ---------------- weight prep: fold BN affine into W, +1 augmented channel ----------------
template<int CINn, int COUTn>
__global__ void k_prepw0(const float* __restrict__ W, float* __restrict__ Wp)
{
  int t = threadIdx.x;
  for (int idx = t; idx < 4*(CINn+1)*COUTn; idx += 256){
    int c = idx % COUTn;
    int rest = idx / COUTn;
    int i = rest % (CINn+1);
    int k = rest / (CINn+1);
    Wp[idx] = (i < CINn) ? W[(k*CINn + i)*COUTn + c] : 0.f;
  }
}

template<int CINn, int COUTn>
__global__ void k_finw(const float* __restrict__ stats, const float* __restrict__ g,
                       const float* __restrict__ b, float* __restrict__ scsh,
                       const float* __restrict__ W, float* __restrict__ Wp, float denomN)
{
  __shared__ float ssc[CINn], ssh[CINn];
  int t = threadIdx.x;
  if (t < CINn){
    float m = stats[t] / denomN;
    float var = stats[CINn+t] / denomN - m*m;
    float scl = g[t] * rsqrtf(var + 1e-5f);
    float shv = fmaf(-m, scl, b[t]);
    scsh[t] = scl; scsh[32+t] = shv;
    ssc[t] = scl; ssh[t] = shv;
  }
  __syncthreads();
  for (int idx = t; idx < 4*(CINn+1)*COUTn; idx += 256){
    int c = idx % COUTn;
    int rest = idx / COUTn;
    int i = rest % (CINn+1);
    int k = rest / (CINn+1);
    float v;
    if (i < CINn) v = ssc[i] * W[(k*CINn + i)*COUTn + c];
    else {
      float acc = 0.f;
      for (int j=0;j<CINn;j++) acc += ssh[j] * W[(k*CINn + j)*COUTn + c];
      v = acc;
    }
    Wp[idx] = v;
  }
}

__global__ void k_fin(const float* __restrict__ stats, const float* __restrict__ g,
                      const float* __restrict__ b, float* __restrict__ scsh,
                      const float* __restrict__ twp, float denomN, int C)
{
  int c = threadIdx.x;
  if (c >= C) return;
  float cntv = twp ? *twp : denomN;
  float m = stats[c] / cntv;
  float var = stats[C+c] / cntv - m*m;
  float scl = g[c] * rsqrtf(var + 1e-5f);
  scsh[c] = scl;
  scsh[32+c] = fmaf(-m, scl, b[c]);
}

// count non-empty cells -> tw (31 atomics total)
__global__ __launch_bounds__(256) void k_twc(const int* __restrict__ hist, float* __restrict__ tw)
{
  int q = blockIdx.x*256 + threadIdx.x;
  int v = (q < SS && hist[q] > 0) ? 1 : 0;
  __shared__ int sh[256];
  sh[threadIdx.x] = v; __syncthreads();
  for (int off=128; off; off>>=1){ if (threadIdx.x<off) sh[threadIdx.x]+=sh[threadIdx.x+off]; __syncthreads(); }
  if (threadIdx.x == 0 && sh[0] > 0) atomicAdd(tw, (float)sh[0]);
}

// ---------------- node spline conv (z-decomposition, 2 thr/node, split epilogue) ----------------
template<int CIN>
__device__ __forceinline__ void loadrow(float* xv, const float* __restrict__ xin, int srcn){
  if constexpr ((CIN & 3) == 0){
    const float4* xr = reinterpret_cast<const float4*>(xin + (size_t)srcn*CIN);
    #pragma unroll
    for (int q=0;q<CIN/4;q++){ float4 t=xr[q]; xv[4*q]=t.x; xv[4*q+1]=t.y; xv[4*q+2]=t.z; xv[4*q+3]=t.w; }
  } else {
    const float2* xr = reinterpret_cast<const float2*>(xin + (size_t)srcn*CIN);
    #pragma unroll
    for (int q=0;q<CIN/2;q++){ float2 t=xr[q]; xv[2*q]=t.x; xv[2*q+1]=t.y; }
  }
}

template<int CIN, int COUT>
__global__ __launch_bounds__(256,4) void k_conv(
    const float* __restrict__ xin, const int* __restrict__ rowstart,
    const uint2* __restrict__ csr, const float* __restrict__ Wp,
    float* __restrict__ aout)
{
  int tid = threadIdx.x;
  int h = tid & 1;
  int lnode = tid >> 1;
  int p = blockIdx.x & 15;
  int i = blockIdx.x >> 4;
  int d = (p << 14) + i*128 + lnode;
  constexpr int ZN = 4*(CIN+1);
  float z[ZN];
  #pragma unroll
  for (int j=0;j<ZN;j++) z[j]=0.f;
  int rs = rowstart[d], re = rowstart[d+1];

  const float Q = 1.f/65535.f;
  auto accum = [&](unsigned fe, const float* xv){
    float fx = (float)(fe & 0xFFFFu) * Q;
    float fy = (float)(fe >> 16) * Q;
    float b1v = fx*(1.f-fy), b2v = (1.f-fx)*fy, b3v = fx*fy;
    float b0v = 1.f - b1v - b2v - b3v;
    #pragma unroll
    for (int k=0;k<CIN;k++){
      float v = xv[k];
      z[k]              = fmaf(b0v, v, z[k]);
      z[(CIN+1)+k]      = fmaf(b1v, v, z[(CIN+1)+k]);
      z[2*(CIN+1)+k]    = fmaf(b2v, v, z[2*(CIN+1)+k]);
      z[3*(CIN+1)+k]    = fmaf(b3v, v, z[3*(CIN+1)+k]);
    }
    z[CIN]             += b0v;
    z[(CIN+1)+CIN]     += b1v;
    z[2*(CIN+1)+CIN]   += b2v;
    z[3*(CIN+1)+CIN]   += b3v;
  };

  int s = rs + h;
  for (; s + 2 < re; s += 4){
    uint2 e0, e1;
    e0.x = __builtin_nontemporal_load(&csr[s].x);
    e0.y = __builtin_nontemporal_load(&csr[s].y);
    e1.x = __builtin_nontemporal_load(&csr[s+2].x);
    e1.y = __builtin_nontemporal_load(&csr[s+2].y);
    float xv0[CIN], xv1[CIN];
    loadrow<CIN>(xv0, xin, (int)e0.x);
    loadrow<CIN>(xv1, xin, (int)e1.x);
    accum(e0.y, xv0);
    accum(e1.y, xv1);
  }
  if (s < re){
    uint2 e0;
    e0.x = __builtin_nontemporal_load(&csr[s].x);
    e0.y = __builtin_nontemporal_load(&csr[s].y);
    float xv0[CIN];
    loadrow<CIN>(xv0, xin, (int)e0.x);
    accum(e0.y, xv0);
  }

  // reduce z across the thread pair (in-place, no extra arrays)
  #pragma unroll
  for (int j=0;j<ZN;j++) z[j] += __shfl_xor(z[j], 1, 64);

  // each thread computes only its half of the output channels
  constexpr int CH = COUT/2;
  float out[CH];
  #pragma unroll
  for (int c=0;c<CH;c++) out[c]=0.f;
  #pragma unroll
  for (int j=0;j<ZN;j++){
    const float* wr = Wp + j*COUT + h*CH;
    float zj = z[j];
    #pragma unroll
    for (int c=0;c<CH;c++) out[c] = fmaf(zj, wr[c], out[c]);
  }

  float invd = 1.f / fmaxf((float)(re - rs), 1.f);
  float* orow = aout + (size_t)d*COUT + h*CH;
  #pragma unroll
  for (int q=0;q<CH/4;q++){
    float4 t;
    t.x = eluf(out[4*q+0]*invd);
    t.y = eluf(out[4*q+1]*invd);
    t.z = eluf(out[4*q+2]*invd);
    t.w = eluf(out[4*q+3]*invd);
    reinterpret_cast<float4*>(orow)[q] = t;
  }
}

// combine two folded-BN activations into one table (input to layer 5)
__global__ __launch_bounds__(256) void k_comb(const float* __restrict__ a, const float* __restrict__ b,
    const float* __restrict__ sA, const float* __restrict__ sB, float* __restrict__ o)
{
  int n = blockIdx.x*256 + threadIdx.x;
  const float4* ar = reinterpret_cast<const float4*>(a + (size_t)n*16);
  const float4* br = reinterpret_cast<const float4*>(b + (size_t)n*16);
  float4* orow = reinterpret_cast<float4*>(o + (size_t)n*16);
  #pragma unroll
  for (int q=0;q<4;q++){
    float4 av=ar[q], bv=br[q];
    float4 r;
    r.x = fmaf(av.x, sA[4*q+0], sA[32+4*q+0]) + fmaf(bv.x, sB[4*q+0], sB[32+4*q+0]);
    r.y = fmaf(av.y, sA[4*q+1], sA[32+4*q+1]) + fmaf(bv.y, sB[4*q+1], sB[32+4*q+1]);
    r.z = fmaf(av.z, sA[4*q+2], sA[32+4*q+2]) + fmaf(bv.z, sB[4*q+2], sB[32+4*q+2]);
    r.w = fmaf(av.w, sA[4*q+3], sA[32+4*q+3]) + fmaf(bv.w, sB[4*q+3], sB[32+4*q+3]);
    orow[q] = r;
  }
}

// ---------------- BN statistics ----------------
template<int C, bool WEIGHTED>
__global__ __launch_bounds__(256) void k_stats(const float* __restrict__ a, const float* __restrict__ wcnt,
                                               float* __restrict__ stats, int n)
{
  int t = blockIdx.x*256 + threadIdx.x;
  int T = gridDim.x*256;
  float s1=0.f, s2=0.f;
  int M = n*C;
  for (int e = t; e < M; e += T){
    float v = __builtin_nontemporal_load(a+e);
    if (WEIGHTED){ if (!(wcnt[e/C] > 0.f)) continue; }
    s1 += v; s2 += v*v;
  }
  __shared__ float sh[256];
  int lt = threadIdx.x;
  sh[lt] = s1; __syncthreads();
  #pragma unroll
  for (int off=128; off>=C; off>>=1){ if (lt<off) sh[lt]+=sh[lt+off]; __syncthreads(); }
  if (lt < C) atomicAdd(&stats[lt], sh[lt]);
  __syncthreads();
  sh[lt] = s2; __syncthreads();
  #pragma unroll
  for (int off=128; off>=C; off>>=1){ if (lt<off) sh[lt]+=sh[lt+off]; __syncthreads(); }
  if (lt < C) atomicAdd(&stats[C+lt], sh[lt]);
}

// ---------------- pooling: counting sort by cell, then block-per-cell gather ----------------
__global__ __launch_bounds__(256) void k_cellhist(const float2* __restrict__ pos,
                      int* __restrict__ cid, int* __restrict__ hist)
{
  int n = blockIdx.x*256 + threadIdx.x;
  float2 p = pos[n];
  const float SXf = (float)(16.0/346.0);
  const float SYf = (float)(12.0/260.0);
  int cx = (int)floorf(p.x / SXf); cx = min(max(cx, 0), 21);
  int cy = (int)floorf(p.y / SYf); cy = min(max(cy, 0), 21);
  int cd = (n >> 14) * GG + cy*22 + cx;
  cid[n] = cd;
  atomicAdd(&hist[cd], 1);
}

__global__ __launch_bounds__(256) void k_cellscatter(const int* __restrict__ cid,
                      const int* __restrict__ cellstart, int* __restrict__ ccur, int* __restrict__ order)
{
  int n = blockIdx.x*256 + threadIdx.x;
  int cd = cid[n];
  int t = atomicAdd(&ccur[cd], 1);
  order[cellstart[cd] + t] = n;
}

// block per cell: 32 node-streams x 8 lanes (float4/lane); graph->XCD swizzle; no global atomics.
__global__ __launch_bounds__(256) void k_poolg(const int* __restrict__ cellstart, const int* __restrict__ order,
    const float2* __restrict__ pos, const float* __restrict__ a5, const float* __restrict__ scsh5,
    float* __restrict__ xpf, float2* __restrict__ pp, float* __restrict__ cntf)
{
  int bb = blockIdx.x;
  int q = (bb & 15)*GG + (bb >> 4);
  int t = threadIdx.x;
  int strm = t >> 3;
  int cg = t & 7;
  int c4 = cg*4;
  int rs = cellstart[q], re = cellstart[q+1];
  float sc0=scsh5[c4+0], sc1=scsh5[c4+1], sc2=scsh5[c4+2], sc3=scsh5[c4+3];
  float sh0=scsh5[32+c4+0], sh1=scsh5[32+c4+1], sh2=scsh5[32+c4+2], sh3=scsh5[32+c4+3];
  float m0=-3.4e38f, m1=-3.4e38f, m2=-3.4e38f, m3=-3.4e38f;
  float psx=0.f, psy=0.f;
  __shared__ int nbuf[256];
  for (int base = rs; base < re; base += 256){
    int ent = min(256, re - base);
    if (t < ent) nbuf[t] = order[base + t];
    __syncthreads();
    for (int j = strm; j < ent; j += 32){
      int n = nbuf[j];
      float4 v = reinterpret_cast<const float4*>(a5 + (size_t)n*32)[cg];
      m0 = fmaxf(m0, fmaf(v.x, sc0, sh0));
      m1 = fmaxf(m1, fmaf(v.y, sc1, sh1));
      m2 = fmaxf(m2, fmaf(v.z, sc2, sh2));
      m3 = fmaxf(m3, fmaf(v.w, sc3, sh3));
      if (cg == 0){ float2 p = pos[n]; psx += p.x; psy += p.y; }
    }
    __syncthreads();
  }
  __shared__ float msh[32][33];
  __shared__ float pshx[32], pshy[32];
  msh[strm][c4+0]=m0; msh[strm][c4+1]=m1; msh[strm][c4+2]=m2; msh[strm][c4+3]=m3;
  if (cg == 0){ pshx[strm]=psx; pshy[strm]=psy; }
  __syncthreads();
  if (t < 32){
    float mm = msh[0][t];
    #pragma unroll
    for (int s2=1; s2<32; s2++) mm = fmaxf(mm, msh[s2][t]);
    int cnt = re - rs;
    xpf[(size_t)q*32 + t] = (cnt > 0) ? mm : 0.f;
    if (t == 0){
      float sx=0.f, sy=0.f;
      #pragma unroll
      for (int s2=0; s2<32; s2++){ sx += pshx[s2]; sy += pshy[s2]; }
      float inv = 1.f / fmaxf((float)cnt, 1.f);
      pp[q] = make_float2(sx*inv, sy*inv);
      cntf[q] = (float)cnt;
    }
  }
}

__global__ __launch_bounds__(256) void k_slot(const int* __restrict__ src, const int* __restrict__ dst,
                      const int* __restrict__ cid, unsigned char* __restrict__ slotb)
{
  int gid = blockIdx.x*256 + threadIdx.x;
  int stride = gridDim.x*256;
  for (int e = gid; e < EE; e += stride){
    int cs = cid[__builtin_nontemporal_load(src+e)];
    int cdd = cid[__builtin_nontemporal_load(dst+e)];
    if (cs != cdd){
      int g = cs / GG;
      slotb[(size_t)cs*GG + (cdd - g*GG)] = 1;
    }
  }
}

__global__ __launch_bounds__(256) void k_pair_deg(const unsigned char* __restrict__ slotb,
                      const float2* __restrict__ pp, int* __restrict__ deg2, unsigned* __restrict__ mxp)
{
  int gid = blockIdx.x*256 + threadIdx.x;
  int stride = gridDim.x*256;
  float lm = 0.f;
  for (int s = gid; s < NSLOT; s += stride){
    if (slotb[s]){
      int cs = s / GG; int lcd = s - cs*GG;
      int g = cs / GG; int cdd = g*GG + lcd;
      atomicAdd(&deg2[cdd], 1);
      float2 a = pp[cs], b = pp[cdd];
      lm = fmaxf(lm, fmaxf(fabsf(a.x-b.x), fabsf(a.y-b.y)));
    }
  }
  __shared__ float sh[256];
  sh[threadIdx.x] = lm; __syncthreads();
  for (int off=128; off; off>>=1){ if (threadIdx.x<off) sh[threadIdx.x]=fmaxf(sh[threadIdx.x],sh[threadIdx.x+off]); __syncthreads(); }
  if (threadIdx.x==0) atomicMax(mxp, __float_as_uint(sh[0]));
}

// fill pair records WITH precomputed (quantized) basis coords
__global__ __launch_bounds__(256) void k_pair_fill(const unsigned char* __restrict__ slotb,
                      const int* __restrict__ rowstart2, int* __restrict__ cursor2,
                      const float2* __restrict__ pp, const float* __restrict__ mxp,
                      uint2* __restrict__ pairrec)
{
  float denom = 2.f * (*mxp) + 1e-12f;
  float rdenom = 1.f / denom;
  int gid = blockIdx.x*256 + threadIdx.x;
  int stride = gridDim.x*256;
  for (int s = gid; s < NSLOT; s += stride){
    if (slotb[s]){
      int cs = s / GG; int lcd = s - cs*GG;
      int g = cs / GG; int cdd = g*GG + lcd;
      float2 a = pp[cs], b = pp[cdd];
      float f0 = fminf(fmaxf(fmaf(a.x - b.x, rdenom, 0.5f), 0.f), 1.f);
      float f1 = fminf(fmaxf(fmaf(a.y - b.y, rdenom, 0.5f), 0.f), 1.f);
      unsigned ux = (unsigned)(f0*65535.f + 0.5f);
      unsigned uy = (unsigned)(f1*65535.f + 0.5f);
      int p = atomicAdd(&cursor2[cdd], 1);
      uint2 rec; rec.x = (unsigned)cs; rec.y = (uy << 16) | ux;
      pairrec[rowstart2[cdd] + p] = rec;
    }
  }
}

// ---------------- pool spline conv: 4 waves/cell, pairrec staged via LDS ----------------
__global__ __launch_bounds__(256) void k_pconv(const float* __restrict__ xin, const float* __restrict__ scsh,
                      const int* __restrict__ rowstart2, const uint2* __restrict__ pairrec,
                      const float* __restrict__ W, float* __restrict__ aout)
{
  int d = blockIdx.x;
  int t = threadIdx.x;
  int wv = t >> 6;
  int l = t & 63;
  int c = l & 31, k0 = l >> 5;
  float scc = 1.f, shc = 0.f;
  if (scsh){ scc = scsh[c]; shc = scsh[32+c]; }
  int rs = rowstart2[d], re = rowstart2[d+1];
  const float Q = 1.f/65535.f;
  float z0 = 0.f, z1 = 0.f;
  __shared__ uint2 ebuf[256];
  for (int base = rs; base < re; base += 256){
    int ent = min(256, re - base);
    if (t < ent) ebuf[t] = pairrec[base + t];
    __syncthreads();
    for (int s = wv; s < ent; s += 4){
      uint2 rec = ebuf[s];
      int cs = (int)rec.x;
      float fx = (float)(rec.y & 0xFFFFu) * Q;
      float fy = (float)(rec.y >> 16) * Q;
      float g0 = k0 ? fx : (1.f - fx);
      float v = fmaf(xin[cs*32 + c], scc, shc);
      z0 = fmaf(g0*(1.f-fy), v, z0);
      z1 = fmaf(g0*fy,       v, z1);
    }
    __syncthreads();
  }
  __shared__ float zsh[4][128];
  zsh[wv][k0*32 + c]     = z0;
  zsh[wv][(2+k0)*32 + c] = z1;
  __syncthreads();
  if (t < 128){
    float zr = zsh[0][t] + zsh[1][t] + zsh[2][t] + zsh[3][t];
    zsh[0][t] = zr;
  }
  __syncthreads();
  int jg = t >> 5;
  int cc = t & 31;
  float part = 0.f;
  #pragma unroll
  for (int j = 0; j < 16; ++j){
    int jj = jg*16 + j;
    part = fmaf(zsh[0][jj], W[jj*32 + cc], part);
  }
  __shared__ float psh[256];
  psh[t] = part;
  __syncthreads();
  if (t < 32){
    float o = 0.f;
    #pragma unroll
    for (int g = 0; g < 8; ++g) o += psh[g*32 + t];
    o /= fmaxf((float)(re - rs), 1.f);
    aout[d*32 + t] = eluf(o);
  }
}

// ---------------- global mean + fc (wide: 16 blocks x 1024 threads) ----------------
__global__ __launch_bounds__(1024) void k_final(const float* __restrict__ a7, const float* __restrict__ scsh7,
                      const float* __restrict__ cnt, const float* __restrict__ fcW, float* __restrict__ outp)
{
  int b = blockIdx.x;
  int t = threadIdx.x;
  int c = t & 31, jg = t >> 5;
  float sc = scsh7[c], sh = scsh7[32+c];
  float acc = 0.f, wn = 0.f;
  for (int j = jg; j < GG; j += 32){
    int d = b*GG + j;
    if (cnt[d] > 0.f){ acc = fmaf(a7[d*32 + c], sc, acc + sh); wn += 1.f; }
  }
  __shared__ float sa[32][33];
  __shared__ float sw[32];
  sa[jg][c] = acc;
  if (c == 0) sw[jg] = wn;
  __syncthreads();
  for (int off=16; off>=1; off>>=1){
    if (jg < off){
      sa[jg][c] += sa[jg+off][c];
      if (c == 0) sw[jg] += sw[jg+off];
    }
    __syncthreads();
  }
  if (t < 32) sa[1][t] = sa[0][t] / sw[0];
  __syncthreads();
  if (t < 10){
    float o = 0.f;
    #pragma unroll
    for (int cc = 0; cc < 32; cc++) o = fmaf(sa[1][cc], fcW[cc*10 + t], o);
    outp[b*10 + t] = o;
  }
}

extern "C" void kernel_launch(void* const* d_in, const int* in_sizes, int n_in,
                              void* d_out, int out_size, void* d_ws, size_t ws_size,
                              hipStream_t stream)
{
  const float*  x    = (const float*)d_in[0];
  const float2* pos  = (const float2*)d_in[1];
  const int*    ei   = (const int*)d_in[3];
  const int*    srcp = ei;
  const int*    dstp = ei + EE;
  const float2* ea   = (const float2*)d_in[4];
  const float* W1=(const float*)d_in[5],  *g1=(const float*)d_in[6],  *b1=(const float*)d_in[7];
  const float* W2=(const float*)d_in[8],  *g2=(const float*)d_in[9],  *b2=(const float*)d_in[10];
  const float* W21=(const float*)d_in[11],*g21=(const float*)d_in[12],*b21=(const float*)d_in[13];
  const float* W3=(const float*)d_in[14], *g3=(const float*)d_in[15], *b3=(const float*)d_in[16];
  const float* W4=(const float*)d_in[17], *g4=(const float*)d_in[18], *b4=(const float*)d_in[19];
  const float* W5=(const float*)d_in[20], *g5=(const float*)d_in[21], *b5=(const float*)d_in[22];
  const float* W6=(const float*)d_in[23], *g6=(const float*)d_in[24], *b6=(const float*)d_in[25];
  const float* W7=(const float*)d_in[26], *g7=(const float*)d_in[27], *b7=(const float*)d_in[28];
  const float* fcW=(const float*)d_in[29];
  float* outp = (float*)d_out;

  char* w = (char*)d_ws;
  size_t off = 0;
  auto take = [&](size_t bytes)->char*{
    char* p = w + off;
    off = (off + bytes + 255) & ~(size_t)255;
    return p;
  };
  // ---- zero region ----
  unsigned char* slotb = (unsigned char*)take((size_t)NSLOT);
  int*      hist    = (int*)      take((size_t)SS*4);
  int*      ccur    = (int*)      take((size_t)SS*4);
  int*      deg2    = (int*)      take((size_t)SS*4);
  int*      cursor2 = (int*)      take((size_t)SS*4);
  float*    stats   = (float*)    take(8*64*4);
  float*    tw      = (float*)    take(256);
  unsigned* mxp     = (unsigned*) take(256);
  size_t zero_bytes = off;
  // ---- written-before-read region (with lifetime aliasing) ----
  int*      rowstart  = (int*)   take((size_t)(NN+1)*4);
  int*      rowstart2 = (int*)   take((size_t)(SS+1)*4);
  int*      cellstart = (int*)   take((size_t)(SS+1)*4);
  int*      bsum      = (int*)   take(1025*4);
  int*      bsum2     = (int*)   take(1025*4);
  int*      bsum3     = (int*)   take(1025*4);
  int*      histA     = (int*)   take((size_t)(NRANGE*NAB+1)*4);
  int*      histS     = (int*)   take((size_t)(NRANGE*NAB+1)*4);
  float*    Wps       = (float*) take(8*4224*4);
  uint2*    csr       = (uint2*) take((size_t)EE*8);
  int*      cid       = (int*)   take((size_t)NN*4);
  int*      order     = (int*)   take((size_t)NN*4);
  uint2*    pairrec   = (uint2*)csr;            // alias: csr dead after layer-5 conv
  float*    scsh      = (float*) take(8*64*4);
  float2*   pp        = (float2*)take((size_t)SS*8);
  float*    xpf       = (float*) take((size_t)SS*32*4);
  float*    cntf      = (float*) take((size_t)SS*4);
  float*    a6        = (float*) take((size_t)SS*32*4);
  float*    a7        = (float*) take((size_t)SS*32*4);
  float*    aP        = (float*) take((size_t)NN*16*4);
  float*    aQ        = (float*) take((size_t)NN*16*4);
  float*    aR        = (float*) take((size_t)NN*16*4);
  float*    a5        = (float*) take((size_t)NN*32*4);
  uint2*    recs      = (uint2*)aP;             // alias: recs lives only k_bscat..k_csrb
  (void)ws_size; (void)in_sizes; (void)n_in; (void)out_size;

  float* Wp1  = Wps + 0*4224;
  float* Wp2  = Wps + 1*4224;
  float* Wp21 = Wps + 2*4224;
  float* Wp3  = Wps + 3*4224;
  float* Wp4  = Wps + 4*4224;
  float* Wp5  = Wps + 5*4224;

  hipMemsetAsync(d_ws, 0, zero_bytes, stream);

  // ---- CSR build: atomic-free 2-level counting sort ----
  k_hist <<<NAB,256,0,stream>>>(dstp, histA);
  k_scan1<<<NRANGE*NAB/256,256,0,stream>>>(histA, histS, bsum, NRANGE*NAB);
  k_scan2<<<1,1024,0,stream>>>(bsum, NRANGE*NAB/256);
  k_scan3<<<NRANGE*NAB/256,256,0,stream>>>(histS, bsum, NRANGE*NAB);
  k_bscat<<<NAB,256,0,stream>>>(srcp, dstp, ea, histS, recs);
  k_csrb <<<NRANGE,256,0,stream>>>(histS, recs, rowstart, csr);

  // ---- cell assignment + counting sort of nodes by cell ----
  k_cellhist   <<<1024,256,0,stream>>>(pos, cid, hist);
  k_twc        <<<31,256,0,stream>>>(hist, tw);
  k_scan1      <<<31,256,0,stream>>>(hist, cellstart, bsum3, SS);
  k_scan2      <<<1,1024,0,stream>>>(bsum3, 31);
  k_scan3      <<<31,256,0,stream>>>(cellstart, bsum3, SS);
  k_cellscatter<<<1024,256,0,stream>>>(cid, cellstart, ccur, order);
  k_slot       <<<1024,256,0,stream>>>(srcp, dstp, cid, slotb);

  // ---- node conv layers ----
  k_prepw0<10,8><<<1,256,0,stream>>>(W1, Wp1);
  k_conv<10,8><<<2048,256,0,stream>>>(x, rowstart, csr, Wp1, aP);
  k_stats<8,false><<<128,256,0,stream>>>(aP, nullptr, stats+0, NN);
  k_finw<8,16><<<1,256,0,stream>>>(stats+0, g1, b1, scsh+0, W2, Wp2, (float)NN);

  k_conv<8,16><<<2048,256,0,stream>>>(aP, rowstart, csr, Wp2, aQ);
  k_stats<16,false><<<128,256,0,stream>>>(aQ, nullptr, stats+64, NN);
  k_finw<16,16><<<1,256,0,stream>>>(stats+64, g2, b2, scsh+64, W21, Wp21, (float)NN);

  k_conv<16,16><<<2048,256,0,stream>>>(aQ, rowstart, csr, Wp21, aR);
  k_stats<16,false><<<128,256,0,stream>>>(aR, nullptr, stats+128, NN);
  k_finw<16,16><<<1,256,0,stream>>>(stats+128, g21, b21, scsh+128, W3, Wp3, (float)NN);

  k_conv<16,16><<<2048,256,0,stream>>>(aR, rowstart, csr, Wp3, aP);
  k_stats<16,false><<<128,256,0,stream>>>(aP, nullptr, stats+192, NN);
  k_finw<16,16><<<1,256,0,stream>>>(stats+192, g3, b3, scsh+192, W4, Wp4, (float)NN);

  k_conv<16,16><<<2048,256,0,stream>>>(aP, rowstart, csr, Wp4, aQ);
  k_stats<16,false><<<128,256,0,stream>>>(aQ, nullptr, stats+256, NN);
  k_fin<<<1,32,0,stream>>>(stats+256, g4, b4, scsh+256, nullptr, (float)NN, 16);

  k_comb<<<1024,256,0,stream>>>(aQ, aR, scsh+256, scsh+128, aP);
  k_prepw0<16,32><<<1,256,0,stream>>>(W5, Wp5);
  k_conv<16,32><<<2048,256,0,stream>>>(aP, rowstart, csr, Wp5, a5);
  k_stats<32,false><<<128,256,0,stream>>>(a5, nullptr, stats+320, NN);
  k_fin<<<1,32,0,stream>>>(stats+320, g5, b5, scsh+320, nullptr, (float)NN, 32);

  // ---- pooling (block per cell, no global atomics) ----
  k_poolg<<<SS,256,0,stream>>>(cellstart, order, pos, a5, scsh+320, xpf, pp, cntf);

  // ---- pair graph (pairrec aliases csr -- csr dead now) ----
  k_pair_deg<<<512,256,0,stream>>>(slotb, pp, deg2, mxp);
  k_scan1<<<31,256,0,stream>>>(deg2, rowstart2, bsum2, SS);
  k_scan2<<<1,1024,0,stream>>>(bsum2, 31);
  k_scan3<<<31,256,0,stream>>>(rowstart2, bsum2, SS);
  k_pair_fill<<<512,256,0,stream>>>(slotb, rowstart2, cursor2, pp, (const float*)mxp, pairrec);

  // ---- pool convs (4 waves/cell, LDS-staged records) ----
  k_pconv<<<SS,256,0,stream>>>(xpf, nullptr, rowstart2, pairrec, W6, a6);
  k_stats<32,true><<<128,256,0,stream>>>(a6, cntf, stats+384, SS);
  k_fin<<<1,32,0,stream>>>(stats+384, g6, b6, scsh+384, tw, 0.f, 32);

  k_pconv<<<SS,256,0,stream>>>(a6, scsh+384, rowstart2, pairrec, W7, a7);
  k_stats<32,true><<<128,256,0,stream>>>(a7, cntf, stats+448, SS);
  k_fin<<<1,32,0,stream>>>(stats+448, g7, b7, scsh+448, tw, 0.f, 32);

  // ---- global mean + fc (wide) ----
  k_final<<<16,1024,0,stream>>>(a7, scsh+448, cntf, fcW, outp);
}

// Round 17
// 1159.517 us; speedup vs baseline: 5.3935x; 5.3935x over previous
//
#include <hip/hip_runtime.h>
#include <math.h>

#define NN 262144
#define EE 2097152
#define BB 16
#define SS 7744
#define GG 484
#define NSLOT (SS*484)
#define NRANGE 128
#define NAB 512
#define ACH 4096

__device__ __forceinline__ float eluf(float x){ return x > 0.f ? x : expm1f(x); }

// ---------------- generic scans ----------------
__global__ __launch_bounds__(256) void k_scan1(const int* __restrict__ in, int* __restrict__ out,
                                               int* __restrict__ bsum, int n)
{
  __shared__ int sh[256];
  int t = threadIdx.x, gid = blockIdx.x*256 + t;
  int v = (gid < n) ? in[gid] : 0;
  sh[t] = v; __syncthreads();
  for (int off=1; off<256; off<<=1){
    int tmp = (t >= off) ? sh[t-off] : 0;
    __syncthreads();
    sh[t] += tmp;
    __syncthreads();
  }
  if (gid < n) out[gid] = sh[t] - v;
  if (t == 255) bsum[blockIdx.x] = sh[255];
}

__global__ __launch_bounds__(1024) void k_scan2(int* __restrict__ bsum, int nb)
{
  __shared__ int sh[1024];
  int t = threadIdx.x;
  int v = (t < nb) ? bsum[t] : 0;
  sh[t] = v; __syncthreads();
  for (int off=1; off<1024; off<<=1){
    int tmp = (t >= off) ? sh[t-off] : 0;
    __syncthreads();
    sh[t] += tmp;
    __syncthreads();
  }
  if (t < nb) bsum[t] = sh[t] - v;
  if (t == nb-1) bsum[1024] = sh[t];
}

__global__ __launch_bounds__(256) void k_scan3(int* __restrict__ out, const int* __restrict__ bsum, int n)
{
  int gid = blockIdx.x*256 + threadIdx.x;
  if (gid < n) out[gid] += bsum[blockIdx.x];
  if (gid == 0) out[n] = bsum[1024];
}

// ---------------- atomic-free CSR build: 2-level counting sort ----------------
__global__ __launch_bounds__(256) void k_hist(const int* __restrict__ dst, int* __restrict__ hist)
{
  __shared__ unsigned h[NRANGE];
  int t = threadIdx.x, b = blockIdx.x;
  if (t < NRANGE) h[t] = 0;
  __syncthreads();
  int base = b*ACH;
  for (int e = base + t; e < base + ACH; e += 256){
    int d = __builtin_nontemporal_load(dst + e);
    atomicAdd(&h[d >> 11], 1u);
  }
  __syncthreads();
  if (t < NRANGE) hist[t*NAB + b] = (int)h[t];
}

__global__ __launch_bounds__(256) void k_bscat(const int* __restrict__ src, const int* __restrict__ dst,
                          const float2* __restrict__ ea, const int* __restrict__ histS,
                          uint2* __restrict__ recs)
{
  __shared__ unsigned cur[NRANGE];
  int t = threadIdx.x, b = blockIdx.x;
  if (t < NRANGE) cur[t] = (unsigned)histS[t*NAB + b];
  __syncthreads();
  int base = b*ACH;
  for (int e = base + t; e < base + ACH; e += 256){
    int d = __builtin_nontemporal_load(dst + e);
    int sv = __builtin_nontemporal_load(src + e);
    float2 f = ea[e];
    unsigned ux = (unsigned)(fminf(fmaxf(f.x, 0.f), 1.f)*65535.f + 0.5f);
    unsigned uy = (unsigned)(fminf(fmaxf(f.y, 0.f), 1.f)*65535.f + 0.5f);
    unsigned pos = atomicAdd(&cur[d >> 11], 1u);
    uint2 rec;
    rec.x = (unsigned)sv | ((unsigned)(d & 2047) << 18);
    rec.y = (uy << 16) | ux;
    recs[pos] = rec;
  }
}

__global__ __launch_bounds__(256) void k_csrb(const int* __restrict__ histS, const uint2* __restrict__ recs,
                          int* __restrict__ rowstart, uint2* __restrict__ csr)
{
  __shared__ unsigned cnt[2048];
  __shared__ unsigned psum[256];
  int t = threadIdx.x, r = blockIdx.x;
  int rs = histS[r*NAB];
  int reE = histS[(r+1)*NAB];
  for (int i = t; i < 2048; i += 256) cnt[i] = 0;
  __syncthreads();
  for (int i = rs + t; i < reE; i += 256){
    unsigned rx = recs[i].x;
    atomicAdd(&cnt[rx >> 18], 1u);
  }
  __syncthreads();
  unsigned loc[8], run = 0;
  #pragma unroll
  for (int j=0;j<8;j++){ loc[j] = run; run += cnt[t*8+j]; }
  psum[t] = run; __syncthreads();
  for (int off=1; off<256; off<<=1){
    unsigned v = (t >= off) ? psum[t-off] : 0;
    __syncthreads();
    psum[t] += v;
    __syncthreads();
  }
  unsigned basep = psum[t] - run;
  #pragma unroll
  for (int j=0;j<8;j++) cnt[t*8+j] = basep + loc[j];
  __syncthreads();
  for (int i = t; i < 2048; i += 256) rowstart[r*2048 + i] = rs + (int)cnt[i];
  if (r == NRANGE-1 && t == 0) rowstart[NN] = EE;
  __syncthreads();
  for (int i = rs + t; i < reE; i += 256){
    uint2 rec = recs[i];
    unsigned dl = rec.x >> 18;
    unsigned slot = atomicAdd(&cnt[dl], 1u);
    uint2 o; o.x = rec.x & 0x3FFFFu; o.y = rec.y;
    csr[(size_t)rs + slot] = o;
  }
}

// ---------------- weight prep: fold BN affine into W, +1 augmented channel ----------------
template<int CINn, int COUTn>
__global__ void k_prepw0(const float* __restrict__ W, float* __restrict__ Wp)
{
  int t = threadIdx.x;
  for (int idx = t; idx < 4*(CINn+1)*COUTn; idx += 256){
    int c = idx % COUTn;
    int rest = idx / COUTn;
    int i = rest % (CINn+1);
    int k = rest / (CINn+1);
    Wp[idx] = (i < CINn) ? W[(k*CINn + i)*COUTn + c] : 0.f;
  }
}

template<int CINn, int COUTn>
__global__ void k_finw(const float* __restrict__ stats, const float* __restrict__ g,
                       const float* __restrict__ b, float* __restrict__ scsh,
                       const float* __restrict__ W, float* __restrict__ Wp, float denomN)
{
  __shared__ float ssc[CINn], ssh[CINn];
  int t = threadIdx.x;
  if (t < CINn){
    float m = stats[t] / denomN;
    float var = stats[CINn+t] / denomN - m*m;
    float scl = g[t] * rsqrtf(var + 1e-5f);
    float shv = fmaf(-m, scl, b[t]);
    scsh[t] = scl; scsh[32+t] = shv;
    ssc[t] = scl; ssh[t] = shv;
  }
  __syncthreads();
  for (int idx = t; idx < 4*(CINn+1)*COUTn; idx += 256){
    int c = idx % COUTn;
    int rest = idx / COUTn;
    int i = rest % (CINn+1);
    int k = rest / (CINn+1);
    float v;
    if (i < CINn) v = ssc[i] * W[(k*CINn + i)*COUTn + c];
    else {
      float acc = 0.f;
      for (int j=0;j<CINn;j++) acc += ssh[j] * W[(k*CINn + j)*COUTn + c];
      v = acc;
    }
    Wp[idx] = v;
  }
}

__global__ void k_fin(const float* __restrict__ stats, const float* __restrict__ g,
                      const float* __restrict__ b, float* __restrict__ scsh,
                      const float* __restrict__ twp, float denomN, int C)
{
  int c = threadIdx.x;
  if (c >= C) return;
  float cntv = twp ? *twp : denomN;
  float m = stats[c] / cntv;
  float var = stats[C+c] / cntv - m*m;
  float scl = g[c] * rsqrtf(var + 1e-5f);
  scsh[c] = scl;
  scsh[32+c] = fmaf(-m, scl, b[c]);
}

// count non-empty cells -> tw (31 atomics total)
__global__ __launch_bounds__(256) void k_twc(const int* __restrict__ hist, float* __restrict__ tw)
{
  int q = blockIdx.x*256 + threadIdx.x;
  int v = (q < SS && hist[q] > 0) ? 1 : 0;
  __shared__ int sh[256];
  sh[threadIdx.x] = v; __syncthreads();
  for (int off=128; off; off>>=1){ if (threadIdx.x<off) sh[threadIdx.x]+=sh[threadIdx.x+off]; __syncthreads(); }
  if (threadIdx.x == 0 && sh[0] > 0) atomicAdd(tw, (float)sh[0]);
}

// ---------------- node spline conv (z-decomposition, 2 thr/node; r15-proven body, DO NOT
// restructure the z array: r5/r7/r16 all spilled when its liveness pattern changed) ----------------
template<int CIN>
__device__ __forceinline__ void loadrow(float* xv, const float* __restrict__ xin, int srcn){
  if constexpr ((CIN & 3) == 0){
    const float4* xr = reinterpret_cast<const float4*>(xin + (size_t)srcn*CIN);
    #pragma unroll
    for (int q=0;q<CIN/4;q++){ float4 t=xr[q]; xv[4*q]=t.x; xv[4*q+1]=t.y; xv[4*q+2]=t.z; xv[4*q+3]=t.w; }
  } else {
    const float2* xr = reinterpret_cast<const float2*>(xin + (size_t)srcn*CIN);
    #pragma unroll
    for (int q=0;q<CIN/2;q++){ float2 t=xr[q]; xv[2*q]=t.x; xv[2*q+1]=t.y; }
  }
}

template<int CIN, int COUT>
__global__ __launch_bounds__(256,4) void k_conv(
    const float* __restrict__ xin, const int* __restrict__ rowstart,
    const uint2* __restrict__ csr, const float* __restrict__ Wp,
    float* __restrict__ aout)
{
  int tid = threadIdx.x;
  int h = tid & 1;
  int lnode = tid >> 1;
  int p = blockIdx.x & 15;
  int i = blockIdx.x >> 4;
  int d = (p << 14) + i*128 + lnode;
  constexpr int ZN = 4*(CIN+1);
  float z[ZN];
  #pragma unroll
  for (int j=0;j<ZN;j++) z[j]=0.f;
  int rs = rowstart[d], re = rowstart[d+1];

  const float Q = 1.f/65535.f;
  auto accum = [&](unsigned fe, const float* xv){
    float fx = (float)(fe & 0xFFFFu) * Q;
    float fy = (float)(fe >> 16) * Q;
    float b1v = fx*(1.f-fy), b2v = (1.f-fx)*fy, b3v = fx*fy;
    float b0v = 1.f - b1v - b2v - b3v;
    #pragma unroll
    for (int k=0;k<CIN;k++){
      float v = xv[k];
      z[k]              = fmaf(b0v, v, z[k]);
      z[(CIN+1)+k]      = fmaf(b1v, v, z[(CIN+1)+k]);
      z[2*(CIN+1)+k]    = fmaf(b2v, v, z[2*(CIN+1)+k]);
      z[3*(CIN+1)+k]    = fmaf(b3v, v, z[3*(CIN+1)+k]);
    }
    z[CIN]             += b0v;
    z[(CIN+1)+CIN]     += b1v;
    z[2*(CIN+1)+CIN]   += b2v;
    z[3*(CIN+1)+CIN]   += b3v;
  };

  int s = rs + h;
  for (; s + 2 < re; s += 4){
    uint2 e0, e1;
    e0.x = __builtin_nontemporal_load(&csr[s].x);
    e0.y = __builtin_nontemporal_load(&csr[s].y);
    e1.x = __builtin_nontemporal_load(&csr[s+2].x);
    e1.y = __builtin_nontemporal_load(&csr[s+2].y);
    float xv0[CIN], xv1[CIN];
    loadrow<CIN>(xv0, xin, (int)e0.x);
    loadrow<CIN>(xv1, xin, (int)e1.x);
    accum(e0.y, xv0);
    accum(e1.y, xv1);
  }
  if (s < re){
    uint2 e0;
    e0.x = __builtin_nontemporal_load(&csr[s].x);
    e0.y = __builtin_nontemporal_load(&csr[s].y);
    float xv0[CIN];
    loadrow<CIN>(xv0, xin, (int)e0.x);
    accum(e0.y, xv0);
  }

  float out[COUT];
  #pragma unroll
  for (int c=0;c<COUT;c++) out[c]=0.f;
  #pragma unroll
  for (int j=0;j<ZN;j++){
    const float* wr = Wp + j*COUT;
    float zj = z[j];
    #pragma unroll
    for (int c=0;c<COUT;c++) out[c] = fmaf(zj, wr[c], out[c]);
  }
  #pragma unroll
  for (int c=0;c<COUT;c++) out[c] += __shfl_xor(out[c], 1, 64);

  float invd = 1.f / fmaxf((float)(re - rs), 1.f);
  float* orow = aout + (size_t)d*COUT + h*(COUT/2);
  #pragma unroll
  for (int q=0;q<COUT/8;q++){
    float4 t;
    t.x = eluf(out[h*(COUT/2)+4*q+0]*invd);
    t.y = eluf(out[h*(COUT/2)+4*q+1]*invd);
    t.z = eluf(out[h*(COUT/2)+4*q+2]*invd);
    t.w = eluf(out[h*(COUT/2)+4*q+3]*invd);
    reinterpret_cast<float4*>(orow)[q] = t;
  }
}

// combine two folded-BN activations into one table (input to layer 5)
__global__ __launch_bounds__(256) void k_comb(const float* __restrict__ a, const float* __restrict__ b,
    const float* __restrict__ sA, const float* __restrict__ sB, float* __restrict__ o)
{
  int n = blockIdx.x*256 + threadIdx.x;
  const float4* ar = reinterpret_cast<const float4*>(a + (size_t)n*16);
  const float4* br = reinterpret_cast<const float4*>(b + (size_t)n*16);
  float4* orow = reinterpret_cast<float4*>(o + (size_t)n*16);
  #pragma unroll
  for (int q=0;q<4;q++){
    float4 av=ar[q], bv=br[q];
    float4 r;
    r.x = fmaf(av.x, sA[4*q+0], sA[32+4*q+0]) + fmaf(bv.x, sB[4*q+0], sB[32+4*q+0]);
    r.y = fmaf(av.y, sA[4*q+1], sA[32+4*q+1]) + fmaf(bv.y, sB[4*q+1], sB[32+4*q+1]);
    r.z = fmaf(av.z, sA[4*q+2], sA[32+4*q+2]) + fmaf(bv.z, sB[4*q+2], sB[32+4*q+2]);
    r.w = fmaf(av.w, sA[4*q+3], sA[32+4*q+3]) + fmaf(bv.w, sB[4*q+3], sB[32+4*q+3]);
    orow[q] = r;
  }
}

// ---------------- BN statistics ----------------
template<int C, bool WEIGHTED>
__global__ __launch_bounds__(256) void k_stats(const float* __restrict__ a, const float* __restrict__ wcnt,
                                               float* __restrict__ stats, int n)
{
  int t = blockIdx.x*256 + threadIdx.x;
  int T = gridDim.x*256;
  float s1=0.f, s2=0.f;
  int M = n*C;
  for (int e = t; e < M; e += T){
    float v = __builtin_nontemporal_load(a+e);
    if (WEIGHTED){ if (!(wcnt[e/C] > 0.f)) continue; }
    s1 += v; s2 += v*v;
  }
  __shared__ float sh[256];
  int lt = threadIdx.x;
  sh[lt] = s1; __syncthreads();
  #pragma unroll
  for (int off=128; off>=C; off>>=1){ if (lt<off) sh[lt]+=sh[lt+off]; __syncthreads(); }
  if (lt < C) atomicAdd(&stats[lt], sh[lt]);
  __syncthreads();
  sh[lt] = s2; __syncthreads();
  #pragma unroll
  for (int off=128; off>=C; off>>=1){ if (lt<off) sh[lt]+=sh[lt+off]; __syncthreads(); }
  if (lt < C) atomicAdd(&stats[C+lt], sh[lt]);
}

// ---------------- pooling: counting sort by cell, then block-per-cell gather ----------------
__global__ __launch_bounds__(256) void k_cellhist(const float2* __restrict__ pos,
                      int* __restrict__ cid, int* __restrict__ hist)
{
  int n = blockIdx.x*256 + threadIdx.x;
  float2 p = pos[n];
  const float SXf = (float)(16.0/346.0);
  const float SYf = (float)(12.0/260.0);
  int cx = (int)floorf(p.x / SXf); cx = min(max(cx, 0), 21);
  int cy = (int)floorf(p.y / SYf); cy = min(max(cy, 0), 21);
  int cd = (n >> 14) * GG + cy*22 + cx;
  cid[n] = cd;
  atomicAdd(&hist[cd], 1);
}

__global__ __launch_bounds__(256) void k_cellscatter(const int* __restrict__ cid,
                      const int* __restrict__ cellstart, int* __restrict__ ccur, int* __restrict__ order)
{
  int n = blockIdx.x*256 + threadIdx.x;
  int cd = cid[n];
  int t = atomicAdd(&ccur[cd], 1);
  order[cellstart[cd] + t] = n;
}

// block per cell: 32 node-streams x 8 lanes (float4/lane); graph->XCD swizzle; no global atomics.
__global__ __launch_bounds__(256) void k_poolg(const int* __restrict__ cellstart, const int* __restrict__ order,
    const float2* __restrict__ pos, const float* __restrict__ a5, const float* __restrict__ scsh5,
    float* __restrict__ xpf, float2* __restrict__ pp, float* __restrict__ cntf)
{
  int bb = blockIdx.x;
  int q = (bb & 15)*GG + (bb >> 4);
  int t = threadIdx.x;
  int strm = t >> 3;
  int cg = t & 7;
  int c4 = cg*4;
  int rs = cellstart[q], re = cellstart[q+1];
  float sc0=scsh5[c4+0], sc1=scsh5[c4+1], sc2=scsh5[c4+2], sc3=scsh5[c4+3];
  float sh0=scsh5[32+c4+0], sh1=scsh5[32+c4+1], sh2=scsh5[32+c4+2], sh3=scsh5[32+c4+3];
  float m0=-3.4e38f, m1=-3.4e38f, m2=-3.4e38f, m3=-3.4e38f;
  float psx=0.f, psy=0.f;
  __shared__ int nbuf[256];
  for (int base = rs; base < re; base += 256){
    int ent = min(256, re - base);
    if (t < ent) nbuf[t] = order[base + t];
    __syncthreads();
    for (int j = strm; j < ent; j += 32){
      int n = nbuf[j];
      float4 v = reinterpret_cast<const float4*>(a5 + (size_t)n*32)[cg];
      m0 = fmaxf(m0, fmaf(v.x, sc0, sh0));
      m1 = fmaxf(m1, fmaf(v.y, sc1, sh1));
      m2 = fmaxf(m2, fmaf(v.z, sc2, sh2));
      m3 = fmaxf(m3, fmaf(v.w, sc3, sh3));
      if (cg == 0){ float2 p = pos[n]; psx += p.x; psy += p.y; }
    }
    __syncthreads();
  }
  __shared__ float msh[32][33];
  __shared__ float pshx[32], pshy[32];
  msh[strm][c4+0]=m0; msh[strm][c4+1]=m1; msh[strm][c4+2]=m2; msh[strm][c4+3]=m3;
  if (cg == 0){ pshx[strm]=psx; pshy[strm]=psy; }
  __syncthreads();
  if (t < 32){
    float mm = msh[0][t];
    #pragma unroll
    for (int s2=1; s2<32; s2++) mm = fmaxf(mm, msh[s2][t]);
    int cnt = re - rs;
    xpf[(size_t)q*32 + t] = (cnt > 0) ? mm : 0.f;
    if (t == 0){
      float sx=0.f, sy=0.f;
      #pragma unroll
      for (int s2=0; s2<32; s2++){ sx += pshx[s2]; sy += pshy[s2]; }
      float inv = 1.f / fmaxf((float)cnt, 1.f);
      pp[q] = make_float2(sx*inv, sy*inv);
      cntf[q] = (float)cnt;
    }
  }
}

__global__ __launch_bounds__(256) void k_slot(const int* __restrict__ src, const int* __restrict__ dst,
                      const int* __restrict__ cid, unsigned char* __restrict__ slotb)
{
  int gid = blockIdx.x*256 + threadIdx.x;
  int stride = gridDim.x*256;
  for (int e = gid; e < EE; e += stride){
    int cs = cid[__builtin_nontemporal_load(src+e)];
    int cdd = cid[__builtin_nontemporal_load(dst+e)];
    if (cs != cdd){
      int g = cs / GG;
      slotb[(size_t)cs*GG + (cdd - g*GG)] = 1;
    }
  }
}

__global__ __launch_bounds__(256) void k_pair_deg(const unsigned char* __restrict__ slotb,
                      const float2* __restrict__ pp, int* __restrict__ deg2, unsigned* __restrict__ mxp)
{
  int gid = blockIdx.x*256 + threadIdx.x;
  int stride = gridDim.x*256;
  float lm = 0.f;
  for (int s = gid; s < NSLOT; s += stride){
    if (slotb[s]){
      int cs = s / GG; int lcd = s - cs*GG;
      int g = cs / GG; int cdd = g*GG + lcd;
      atomicAdd(&deg2[cdd], 1);
      float2 a = pp[cs], b = pp[cdd];
      lm = fmaxf(lm, fmaxf(fabsf(a.x-b.x), fabsf(a.y-b.y)));
    }
  }
  __shared__ float sh[256];
  sh[threadIdx.x] = lm; __syncthreads();
  for (int off=128; off; off>>=1){ if (threadIdx.x<off) sh[threadIdx.x]=fmaxf(sh[threadIdx.x],sh[threadIdx.x+off]); __syncthreads(); }
  if (threadIdx.x==0) atomicMax(mxp, __float_as_uint(sh[0]));
}

// fill pair records WITH precomputed (quantized) basis coords
__global__ __launch_bounds__(256) void k_pair_fill(const unsigned char* __restrict__ slotb,
                      const int* __restrict__ rowstart2, int* __restrict__ cursor2,
                      const float2* __restrict__ pp, const float* __restrict__ mxp,
                      uint2* __restrict__ pairrec)
{
  float denom = 2.f * (*mxp) + 1e-12f;
  float rdenom = 1.f / denom;
  int gid = blockIdx.x*256 + threadIdx.x;
  int stride = gridDim.x*256;
  for (int s = gid; s < NSLOT; s += stride){
    if (slotb[s]){
      int cs = s / GG; int lcd = s - cs*GG;
      int g = cs / GG; int cdd = g*GG + lcd;
      float2 a = pp[cs], b = pp[cdd];
      float f0 = fminf(fmaxf(fmaf(a.x - b.x, rdenom, 0.5f), 0.f), 1.f);
      float f1 = fminf(fmaxf(fmaf(a.y - b.y, rdenom, 0.5f), 0.f), 1.f);
      unsigned ux = (unsigned)(f0*65535.f + 0.5f);
      unsigned uy = (unsigned)(f1*65535.f + 0.5f);
      int p = atomicAdd(&cursor2[cdd], 1);
      uint2 rec; rec.x = (unsigned)cs; rec.y = (uy << 16) | ux;
      pairrec[rowstart2[cdd] + p] = rec;
    }
  }
}

// ---------------- pool spline conv: 4 waves/cell, pairrec staged via LDS ----------------
__global__ __launch_bounds__(256) void k_pconv(const float* __restrict__ xin, const float* __restrict__ scsh,
                      const int* __restrict__ rowstart2, const uint2* __restrict__ pairrec,
                      const float* __restrict__ W, float* __restrict__ aout)
{
  int d = blockIdx.x;
  int t = threadIdx.x;
  int wv = t >> 6;
  int l = t & 63;
  int c = l & 31, k0 = l >> 5;
  float scc = 1.f, shc = 0.f;
  if (scsh){ scc = scsh[c]; shc = scsh[32+c]; }
  int rs = rowstart2[d], re = rowstart2[d+1];
  const float Q = 1.f/65535.f;
  float z0 = 0.f, z1 = 0.f;
  __shared__ uint2 ebuf[256];
  for (int base = rs; base < re; base += 256){
    int ent = min(256, re - base);
    if (t < ent) ebuf[t] = pairrec[base + t];
    __syncthreads();
    for (int s = wv; s < ent; s += 4){
      uint2 rec = ebuf[s];
      int cs = (int)rec.x;
      float fx = (float)(rec.y & 0xFFFFu) * Q;
      float fy = (float)(rec.y >> 16) * Q;
      float g0 = k0 ? fx : (1.f - fx);
      float v = fmaf(xin[cs*32 + c], scc, shc);
      z0 = fmaf(g0*(1.f-fy), v, z0);
      z1 = fmaf(g0*fy,       v, z1);
    }
    __syncthreads();
  }
  __shared__ float zsh[4][128];
  zsh[wv][k0*32 + c]     = z0;
  zsh[wv][(2+k0)*32 + c] = z1;
  __syncthreads();
  if (t < 128){
    float zr = zsh[0][t] + zsh[1][t] + zsh[2][t] + zsh[3][t];
    zsh[0][t] = zr;
  }
  __syncthreads();
  int jg = t >> 5;
  int cc = t & 31;
  float part = 0.f;
  #pragma unroll
  for (int j = 0; j < 16; ++j){
    int jj = jg*16 + j;
    part = fmaf(zsh[0][jj], W[jj*32 + cc], part);
  }
  __shared__ float psh[256];
  psh[t] = part;
  __syncthreads();
  if (t < 32){
    float o = 0.f;
    #pragma unroll
    for (int g = 0; g < 8; ++g) o += psh[g*32 + t];
    o /= fmaxf((float)(re - rs), 1.f);
    aout[d*32 + t] = eluf(o);
  }
}

// ---------------- global mean + fc (wide: 16 blocks x 1024 threads) ----------------
__global__ __launch_bounds__(1024) void k_final(const float* __restrict__ a7, const float* __restrict__ scsh7,
                      const float* __restrict__ cnt, const float* __restrict__ fcW, float* __restrict__ outp)
{
  int b = blockIdx.x;
  int t = threadIdx.x;
  int c = t & 31, jg = t >> 5;
  float sc = scsh7[c], sh = scsh7[32+c];
  float acc = 0.f, wn = 0.f;
  for (int j = jg; j < GG; j += 32){
    int d = b*GG + j;
    if (cnt[d] > 0.f){ acc = fmaf(a7[d*32 + c], sc, acc + sh); wn += 1.f; }
  }
  __shared__ float sa[32][33];
  __shared__ float sw[32];
  sa[jg][c] = acc;
  if (c == 0) sw[jg] = wn;
  __syncthreads();
  for (int off=16; off>=1; off>>=1){
    if (jg < off){
      sa[jg][c] += sa[jg+off][c];
      if (c == 0) sw[jg] += sw[jg+off];
    }
    __syncthreads();
  }
  if (t < 32) sa[1][t] = sa[0][t] / sw[0];
  __syncthreads();
  if (t < 10){
    float o = 0.f;
    #pragma unroll
    for (int cc = 0; cc < 32; cc++) o = fmaf(sa[1][cc], fcW[cc*10 + t], o);
    outp[b*10 + t] = o;
  }
}

extern "C" void kernel_launch(void* const* d_in, const int* in_sizes, int n_in,
                              void* d_out, int out_size, void* d_ws, size_t ws_size,
                              hipStream_t stream)
{
  const float*  x    = (const float*)d_in[0];
  const float2* pos  = (const float2*)d_in[1];
  const int*    ei   = (const int*)d_in[3];
  const int*    srcp = ei;
  const int*    dstp = ei + EE;
  const float2* ea   = (const float2*)d_in[4];
  const float* W1=(const float*)d_in[5],  *g1=(const float*)d_in[6],  *b1=(const float*)d_in[7];
  const float* W2=(const float*)d_in[8],  *g2=(const float*)d_in[9],  *b2=(const float*)d_in[10];
  const float* W21=(const float*)d_in[11],*g21=(const float*)d_in[12],*b21=(const float*)d_in[13];
  const float* W3=(const float*)d_in[14], *g3=(const float*)d_in[15], *b3=(const float*)d_in[16];
  const float* W4=(const float*)d_in[17], *g4=(const float*)d_in[18], *b4=(const float*)d_in[19];
  const float* W5=(const float*)d_in[20], *g5=(const float*)d_in[21], *b5=(const float*)d_in[22];
  const float* W6=(const float*)d_in[23], *g6=(const float*)d_in[24], *b6=(const float*)d_in[25];
  const float* W7=(const float*)d_in[26], *g7=(const float*)d_in[27], *b7=(const float*)d_in[28];
  const float* fcW=(const float*)d_in[29];
  float* outp = (float*)d_out;

  char* w = (char*)d_ws;
  size_t off = 0;
  auto take = [&](size_t bytes)->char*{
    char* p = w + off;
    off = (off + bytes + 255) & ~(size_t)255;
    return p;
  };
  // ---- zero region ----
  unsigned char* slotb = (unsigned char*)take((size_t)NSLOT);
  int*      hist    = (int*)      take((size_t)SS*4);
  int*      ccur    = (int*)      take((size_t)SS*4);
  int*      deg2    = (int*)      take((size_t)SS*4);
  int*      cursor2 = (int*)      take((size_t)SS*4);
  float*    stats   = (float*)    take(8*64*4);
  float*    tw      = (float*)    take(256);
  unsigned* mxp     = (unsigned*) take(256);
  size_t zero_bytes = off;
  // ---- written-before-read region (with lifetime aliasing) ----
  int*      rowstart  = (int*)   take((size_t)(NN+1)*4);
  int*      rowstart2 = (int*)   take((size_t)(SS+1)*4);
  int*      cellstart = (int*)   take((size_t)(SS+1)*4);
  int*      bsum      = (int*)   take(1025*4);
  int*      bsum2     = (int*)   take(1025*4);
  int*      bsum3     = (int*)   take(1025*4);
  int*      histA     = (int*)   take((size_t)(NRANGE*NAB+1)*4);
  int*      histS     = (int*)   take((size_t)(NRANGE*NAB+1)*4);
  float*    Wps       = (float*) take(8*4224*4);
  uint2*    csr       = (uint2*) take((size_t)EE*8);
  int*      cid       = (int*)   take((size_t)NN*4);
  int*      order     = (int*)   take((size_t)NN*4);
  uint2*    pairrec   = (uint2*)csr;            // alias: csr dead after layer-5 conv
  float*    scsh      = (float*) take(8*64*4);
  float2*   pp        = (float2*)take((size_t)SS*8);
  float*    xpf       = (float*) take((size_t)SS*32*4);
  float*    cntf      = (float*) take((size_t)SS*4);
  float*    a6        = (float*) take((size_t)SS*32*4);
  float*    a7        = (float*) take((size_t)SS*32*4);
  float*    aP        = (float*) take((size_t)NN*16*4);
  float*    aQ        = (float*) take((size_t)NN*16*4);
  float*    aR        = (float*) take((size_t)NN*16*4);
  float*    a5        = (float*) take((size_t)NN*32*4);
  uint2*    recs      = (uint2*)aP;             // alias: recs lives only k_bscat..k_csrb
  (void)ws_size; (void)in_sizes; (void)n_in; (void)out_size;

  float* Wp1  = Wps + 0*4224;
  float* Wp2  = Wps + 1*4224;
  float* Wp21 = Wps + 2*4224;
  float* Wp3  = Wps + 3*4224;
  float* Wp4  = Wps + 4*4224;
  float* Wp5  = Wps + 5*4224;

  hipMemsetAsync(d_ws, 0, zero_bytes, stream);

  // ---- CSR build: atomic-free 2-level counting sort ----
  k_hist <<<NAB,256,0,stream>>>(dstp, histA);
  k_scan1<<<NRANGE*NAB/256,256,0,stream>>>(histA, histS, bsum, NRANGE*NAB);
  k_scan2<<<1,1024,0,stream>>>(bsum, NRANGE*NAB/256);
  k_scan3<<<NRANGE*NAB/256,256,0,stream>>>(histS, bsum, NRANGE*NAB);
  k_bscat<<<NAB,256,0,stream>>>(srcp, dstp, ea, histS, recs);
  k_csrb <<<NRANGE,256,0,stream>>>(histS, recs, rowstart, csr);

  // ---- cell assignment + counting sort of nodes by cell ----
  k_cellhist   <<<1024,256,0,stream>>>(pos, cid, hist);
  k_twc        <<<31,256,0,stream>>>(hist, tw);
  k_scan1      <<<31,256,0,stream>>>(hist, cellstart, bsum3, SS);
  k_scan2      <<<1,1024,0,stream>>>(bsum3, 31);
  k_scan3      <<<31,256,0,stream>>>(cellstart, bsum3, SS);
  k_cellscatter<<<1024,256,0,stream>>>(cid, cellstart, ccur, order);
  k_slot       <<<1024,256,0,stream>>>(srcp, dstp, cid, slotb);

  // ---- node conv layers ----
  k_prepw0<10,8><<<1,256,0,stream>>>(W1, Wp1);
  k_conv<10,8><<<2048,256,0,stream>>>(x, rowstart, csr, Wp1, aP);
  k_stats<8,false><<<128,256,0,stream>>>(aP, nullptr, stats+0, NN);
  k_finw<8,16><<<1,256,0,stream>>>(stats+0, g1, b1, scsh+0, W2, Wp2, (float)NN);

  k_conv<8,16><<<2048,256,0,stream>>>(aP, rowstart, csr, Wp2, aQ);
  k_stats<16,false><<<128,256,0,stream>>>(aQ, nullptr, stats+64, NN);
  k_finw<16,16><<<1,256,0,stream>>>(stats+64, g2, b2, scsh+64, W21, Wp21, (float)NN);

  k_conv<16,16><<<2048,256,0,stream>>>(aQ, rowstart, csr, Wp21, aR);
  k_stats<16,false><<<128,256,0,stream>>>(aR, nullptr, stats+128, NN);
  k_finw<16,16><<<1,256,0,stream>>>(stats+128, g21, b21, scsh+128, W3, Wp3, (float)NN);

  k_conv<16,16><<<2048,256,0,stream>>>(aR, rowstart, csr, Wp3, aP);
  k_stats<16,false><<<128,256,0,stream>>>(aP, nullptr, stats+192, NN);
  k_finw<16,16><<<1,256,0,stream>>>(stats+192, g3, b3, scsh+192, W4, Wp4, (float)NN);

  k_conv<16,16><<<2048,256,0,stream>>>(aP, rowstart, csr, Wp4, aQ);
  k_stats<16,false><<<128,256,0,stream>>>(aQ, nullptr, stats+256, NN);
  k_fin<<<1,32,0,stream>>>(stats+256, g4, b4, scsh+256, nullptr, (float)NN, 16);

  k_comb<<<1024,256,0,stream>>>(aQ, aR, scsh+256, scsh+128, aP);
  k_prepw0<16,32><<<1,256,0,stream>>>(W5, Wp5);
  k_conv<16,32><<<2048,256,0,stream>>>(aP, rowstart, csr, Wp5, a5);
  k_stats<32,false><<<128,256,0,stream>>>(a5, nullptr, stats+320, NN);
  k_fin<<<1,32,0,stream>>>(stats+320, g5, b5, scsh+320, nullptr, (float)NN, 32);

  // ---- pooling (block per cell, no global atomics) ----
  k_poolg<<<SS,256,0,stream>>>(cellstart, order, pos, a5, scsh+320, xpf, pp, cntf);

  // ---- pair graph (pairrec aliases csr -- csr dead now) ----
  k_pair_deg<<<512,256,0,stream>>>(slotb, pp, deg2, mxp);
  k_scan1<<<31,256,0,stream>>>(deg2, rowstart2, bsum2, SS);
  k_scan2<<<1,1024,0,stream>>>(bsum2, 31);
  k_scan3<<<31,256,0,stream>>>(rowstart2, bsum2, SS);
  k_pair_fill<<<512,256,0,stream>>>(slotb, rowstart2, cursor2, pp, (const float*)mxp, pairrec);

  // ---- pool convs (4 waves/cell, LDS-staged records) ----
  k_pconv<<<SS,256,0,stream>>>(xpf, nullptr, rowstart2, pairrec, W6, a6);
  k_stats<32,true><<<128,256,0,stream>>>(a6, cntf, stats+384, SS);
  k_fin<<<1,32,0,stream>>>(stats+384, g6, b6, scsh+384, tw, 0.f, 32);

  k_pconv<<<SS,256,0,stream>>>(a6, scsh+384, rowstart2, pairrec, W7, a7);
  k_stats<32,true><<<128,256,0,stream>>>(a7, cntf, stats+448, SS);
  k_fin<<<1,32,0,stream>>>(stats+448, g7, b7, scsh+448, tw, 0.f, 32);

  // ---- global mean + fc (wide) ----
  k_final<<<16,1024,0,stream>>>(a7, scsh+448, cntf, fcW, outp);
}